// Round 2
// baseline (386.634 us; speedup 1.0000x reference)
//
#include <hip/hip_runtime.h>
#include <hip/hip_bf16.h>

// DeepseekV2 MoE layer: M=1024 tokens, H=1024 hidden, E=16 experts (top-6 via
// 8 groups-of-2 -> top-3 groups), N=1024 per-expert intermediate, shared
// expert I=2048. fp32 inputs; GEMMs in bf16 MFMA (threshold 2.2e-2).
// R1: BK=64, XOR-swizzled LDS (kills 8-way bank conflicts), mlp2 128x128 tile.

#define M_TOK 1024
#define HDIM  1024
#define NEXP  16
#define NMOE  1024
#define NSH   2048

using bf16x8 = __attribute__((ext_vector_type(8))) short;
using f32x4  = __attribute__((ext_vector_type(4))) float;

static __device__ __forceinline__ short f2b(float x) {
  __hip_bfloat16 b = __float2bfloat16(x);
  return __builtin_bit_cast(short, b);
}

static __device__ __forceinline__ uint4 pack8(float4 a, float4 b) {
  union { short s[8]; uint4 u; } r;
  r.s[0] = f2b(a.x); r.s[1] = f2b(a.y); r.s[2] = f2b(a.z); r.s[3] = f2b(a.w);
  r.s[4] = f2b(b.x); r.s[5] = f2b(b.y); r.s[6] = f2b(b.z); r.s[7] = f2b(b.w);
  return r.u;
}

// LDS tile: rows of 128B (64 bf16), chunk = 16B slot index 0..7.
// XOR swizzle spreads the 8 chunks across the 8 4-bank groups per 8-row stripe.
static __device__ __forceinline__ int swz(int row, int chunk) {
  return (row << 7) + (((chunk ^ row) & 7) << 4);
}

// ---------------- router: logits + softmax + grouped top-k ----------------
__global__ __launch_bounds__(256)
void k_router(const float* __restrict__ hs, const float* __restrict__ gw,
              float* __restrict__ comb, unsigned* __restrict__ maskbuf) {
  int wave = threadIdx.x >> 6, lane = threadIdx.x & 63;
  int tok = blockIdx.x * 4 + wave;
  const float* hrow = hs + (size_t)tok * HDIM;
  float acc[16];
#pragma unroll
  for (int e = 0; e < 16; e++) acc[e] = 0.f;
  for (int h0 = 0; h0 < HDIM; h0 += 64) {
    float x = hrow[h0 + lane];
#pragma unroll
    for (int e = 0; e < 16; e++) acc[e] = fmaf(x, gw[e * HDIM + h0 + lane], acc[e]);
  }
#pragma unroll
  for (int e = 0; e < 16; e++) {
    float v = acc[e];
#pragma unroll
    for (int off = 32; off; off >>= 1) v += __shfl_xor(v, off);
    acc[e] = v;
  }
  float mx = acc[0];
#pragma unroll
  for (int e = 1; e < 16; e++) mx = fmaxf(mx, acc[e]);
  float sum = 0.f;
#pragma unroll
  for (int e = 0; e < 16; e++) { acc[e] = __expf(acc[e] - mx); sum += acc[e]; }
  float inv = 1.f / sum;
#pragma unroll
  for (int e = 0; e < 16; e++) acc[e] *= inv;
  float gs[8];
#pragma unroll
  for (int g = 0; g < 8; g++) gs[g] = fmaxf(acc[2 * g], acc[2 * g + 1]);
  unsigned gmask = 0;
  for (int t = 0; t < 3; t++) {
    int best = 0; float bv = -1.f;
#pragma unroll
    for (int g = 0; g < 8; g++) {
      bool take = (((gmask >> g) & 1u) == 0u) && (gs[g] > bv);
      bv = take ? gs[g] : bv;
      best = take ? g : best;
    }
    gmask |= 1u << best;
  }
  unsigned emask = 0;
#pragma unroll
  for (int g = 0; g < 8; g++) if ((gmask >> g) & 1u) emask |= 3u << (2 * g);
  if (lane < 16) comb[tok * 16 + lane] = ((emask >> lane) & 1u) ? acc[lane] : 0.f;
  if (lane == 0) maskbuf[tok] = emask;
}

// ---------------- per-expert token list compaction ----------------
__global__ __launch_bounds__(1024)
void k_build_lists(const unsigned* __restrict__ maskbuf, int* __restrict__ lists,
                   int* __restrict__ counts, int* __restrict__ offsets) {
  int e = threadIdx.x >> 6, lane = threadIdx.x & 63;
  int cnt = 0;
  for (int c = 0; c < 16; c++) {
    int tok = c * 64 + lane;
    bool sel = (maskbuf[tok] >> e) & 1u;
    unsigned long long b = __ballot(sel);
    if (sel) {
      int pos = cnt + __popcll(b & ((1ull << lane) - 1ull));
      lists[e * 1024 + pos] = tok;
    }
    cnt += __popcll(b);
  }
  for (int i = cnt + lane; i < 1024; i += 64) lists[e * 1024 + i] = 0;  // safe tail
  if (lane == 0) counts[e] = cnt;
  __syncthreads();
  if (threadIdx.x == 0) {
    int run = 0;
    for (int ee = 0; ee < 16; ee++) { offsets[ee] = run; run += counts[ee]; }
  }
}

// ---------------- GEMM1: g = silu(A@Wg^T) * (A@Wu^T), bf16 out ----------------
// tile: 128 rows x (64 gate + 64 up) cols, BK=64, 4 waves (2x2), wave 64x(32+32).
__global__ __launch_bounds__(256)
void k_mlp1(const float* __restrict__ A, const float* __restrict__ W,
            __hip_bfloat16* __restrict__ G,
            const int* __restrict__ lists, const int* __restrict__ counts,
            const int* __restrict__ offsets, int N) {
  int e = blockIdx.z;
  int n0 = blockIdx.x * 64;
  int m0 = blockIdx.y * 128;
  int count = lists ? counts[e] : M_TOK;
  if (m0 >= count) return;
  int gbase = (lists ? offsets[e] : 0) + m0;
  const float* We = W + (size_t)e * (2 * (size_t)N) * HDIM;

  __shared__ short sA[128 * 64];
  __shared__ short sB[128 * 64];  // rows 0-63: gate cols, rows 64-127: up cols
  __shared__ int sTok[128];
  char* cA = (char*)sA; char* cB = (char*)sB;

  int tid = threadIdx.x;
  if (tid < 128) sTok[tid] = lists ? lists[e * 1024 + m0 + tid] : (m0 + tid);
  __syncthreads();

  int srow = tid >> 1, shalf = tid & 1;  // each thread: 32 fp32 of one row-half
  const float* pA = A + (size_t)sTok[srow] * HDIM + shalf * 32;
  int brow = (srow < 64) ? (n0 + srow) : ((int)N + n0 + srow - 64);
  const float* pB = We + (size_t)brow * HDIM + shalf * 32;

  int lane = tid & 63, wave = tid >> 6;
  int wm = wave >> 1, wn = wave & 1;
  int lrow = lane & 15, lquad = lane >> 4;

  f32x4 acc1[4][2] = {};
  f32x4 acc2[4][2] = {};

  for (int k0 = 0; k0 < HDIM; k0 += 64) {
    float4 va[8], vb[8];
#pragma unroll
    for (int i = 0; i < 8; i++) {
      va[i] = *reinterpret_cast<const float4*>(pA + k0 + i * 4);
      vb[i] = *reinterpret_cast<const float4*>(pB + k0 + i * 4);
    }
    __syncthreads();
#pragma unroll
    for (int c = 0; c < 4; c++) {
      *reinterpret_cast<uint4*>(cA + swz(srow, shalf * 4 + c)) = pack8(va[2 * c], va[2 * c + 1]);
      *reinterpret_cast<uint4*>(cB + swz(srow, shalf * 4 + c)) = pack8(vb[2 * c], vb[2 * c + 1]);
    }
    __syncthreads();
#pragma unroll
    for (int ks = 0; ks < 2; ks++) {
      bf16x8 af[4], bg[2], bu[2];
#pragma unroll
      for (int mi = 0; mi < 4; mi++)
        af[mi] = *reinterpret_cast<const bf16x8*>(cA + swz(wm * 64 + mi * 16 + lrow, ks * 4 + lquad));
#pragma unroll
      for (int ni = 0; ni < 2; ni++) {
        bg[ni] = *reinterpret_cast<const bf16x8*>(cB + swz(wn * 32 + ni * 16 + lrow, ks * 4 + lquad));
        bu[ni] = *reinterpret_cast<const bf16x8*>(cB + swz(64 + wn * 32 + ni * 16 + lrow, ks * 4 + lquad));
      }
#pragma unroll
      for (int mi = 0; mi < 4; mi++)
#pragma unroll
        for (int ni = 0; ni < 2; ni++) {
          acc1[mi][ni] = __builtin_amdgcn_mfma_f32_16x16x32_bf16(af[mi], bg[ni], acc1[mi][ni], 0, 0, 0);
          acc2[mi][ni] = __builtin_amdgcn_mfma_f32_16x16x32_bf16(af[mi], bu[ni], acc2[mi][ni], 0, 0, 0);
        }
    }
  }
#pragma unroll
  for (int mi = 0; mi < 4; mi++)
#pragma unroll
    for (int r = 0; r < 4; r++) {
      int li = wm * 64 + mi * 16 + lquad * 4 + r;
      if (m0 + li < count) {
#pragma unroll
        for (int ni = 0; ni < 2; ni++) {
          float x = acc1[mi][ni][r], y = acc2[mi][ni][r];
          float gv = (x / (1.f + __expf(-x))) * y;
          G[(size_t)(gbase + li) * N + (n0 + wn * 32 + ni * 16 + lrow)] = __float2bfloat16(gv);
        }
      }
    }
}

// ---------------- GEMM2: out = g @ W2^T (store or weighted atomic-add) ----------------
// tile: 128 rows x 128 cols, BK=64, 4 waves (2x2), wave 64x64, acc 4x4.
__global__ __launch_bounds__(256)
void k_mlp2(const __hip_bfloat16* __restrict__ Gm, const float* __restrict__ W2,
            float* __restrict__ out,
            const int* __restrict__ lists, const int* __restrict__ counts,
            const int* __restrict__ offsets, const float* __restrict__ comb,
            int K, int mode) {
  int e = blockIdx.z;
  int h0 = blockIdx.x * 128;
  int m0 = blockIdx.y * 128;
  int count = lists ? counts[e] : M_TOK;
  if (m0 >= count) return;
  int abase = (lists ? offsets[e] : 0) + m0;
  const float* We = W2 + (size_t)e * HDIM * K;

  __shared__ short sA[128 * 64];
  __shared__ short sB[128 * 64];
  __shared__ int sTok[128];
  char* cA = (char*)sA; char* cB = (char*)sB;

  int tid = threadIdx.x;
  if (tid < 128) sTok[tid] = lists ? lists[e * 1024 + m0 + tid] : (m0 + tid);
  __syncthreads();

  int srow = tid >> 1, shalf = tid & 1;
  const __hip_bfloat16* pA = Gm + (size_t)(abase + srow) * K + shalf * 32;  // bf16: 32 elem = 64B
  const float* pB = We + (size_t)(h0 + srow) * K + shalf * 32;

  int lane = tid & 63, wave = tid >> 6;
  int wm = wave >> 1, wn = wave & 1;
  int lrow = lane & 15, lquad = lane >> 4;

  f32x4 acc[4][4] = {};

  for (int k0 = 0; k0 < K; k0 += 64) {
    uint4 ua[4]; float4 vb[8];
#pragma unroll
    for (int i = 0; i < 4; i++) ua[i] = *reinterpret_cast<const uint4*>(pA + k0 + i * 8);
#pragma unroll
    for (int i = 0; i < 8; i++) vb[i] = *reinterpret_cast<const float4*>(pB + k0 + i * 4);
    __syncthreads();
#pragma unroll
    for (int c = 0; c < 4; c++) {
      *reinterpret_cast<uint4*>(cA + swz(srow, shalf * 4 + c)) = ua[c];
      *reinterpret_cast<uint4*>(cB + swz(srow, shalf * 4 + c)) = pack8(vb[2 * c], vb[2 * c + 1]);
    }
    __syncthreads();
#pragma unroll
    for (int ks = 0; ks < 2; ks++) {
      bf16x8 af[4], bfr[4];
#pragma unroll
      for (int i = 0; i < 4; i++) {
        af[i]  = *reinterpret_cast<const bf16x8*>(cA + swz(wm * 64 + i * 16 + lrow, ks * 4 + lquad));
        bfr[i] = *reinterpret_cast<const bf16x8*>(cB + swz(wn * 64 + i * 16 + lrow, ks * 4 + lquad));
      }
#pragma unroll
      for (int mi = 0; mi < 4; mi++)
#pragma unroll
        for (int ni = 0; ni < 4; ni++)
          acc[mi][ni] = __builtin_amdgcn_mfma_f32_16x16x32_bf16(af[mi], bfr[ni], acc[mi][ni], 0, 0, 0);
    }
  }

  if (mode == 0) {
#pragma unroll
    for (int mi = 0; mi < 4; mi++)
#pragma unroll
      for (int r = 0; r < 4; r++) {
        int li = wm * 64 + mi * 16 + lquad * 4 + r;
        size_t orow = (size_t)(m0 + li) * HDIM;
#pragma unroll
        for (int ni = 0; ni < 4; ni++)
          out[orow + h0 + wn * 64 + ni * 16 + lrow] = acc[mi][ni][r];
      }
  } else {
#pragma unroll
    for (int mi = 0; mi < 4; mi++)
#pragma unroll
      for (int r = 0; r < 4; r++) {
        int li = wm * 64 + mi * 16 + lquad * 4 + r;
        bool ok = (m0 + li) < count;
        int tok = sTok[li];
        float w = comb[tok * 16 + e];
#pragma unroll
        for (int ni = 0; ni < 4; ni++)
          if (ok) atomicAdd(&out[(size_t)tok * HDIM + h0 + wn * 64 + ni * 16 + lrow],
                            acc[mi][ni][r] * w);
      }
  }
}

extern "C" void kernel_launch(void* const* d_in, const int* in_sizes, int n_in,
                              void* d_out, int out_size, void* d_ws, size_t ws_size,
                              hipStream_t stream) {
  const float* hs  = (const float*)d_in[0];
  const float* gw  = (const float*)d_in[1];
  const float* w1  = (const float*)d_in[2];
  const float* w2  = (const float*)d_in[3];
  const float* sgu = (const float*)d_in[4];
  const float* sd  = (const float*)d_in[5];
  float* out = (float*)d_out;
  char* ws = (char*)d_ws;

  float*    comb    = (float*)(ws + 0);          // 65536 B
  unsigned* maskbuf = (unsigned*)(ws + 65536);   // 4096 B
  int*      lists   = (int*)(ws + 69632);        // 65536 B
  int*      counts  = (int*)(ws + 135168);
  int*      offsets = (int*)(ws + 135232);
  __hip_bfloat16* Gr = (__hip_bfloat16*)(ws + 262144);              // 6272*1024*2
  __hip_bfloat16* Gs = (__hip_bfloat16*)(ws + 262144 + 12845056);   // 1024*2048*2
  if (ws_size < (size_t)(262144 + 12845056 + 4194304)) return;

  k_router<<<dim3(256), dim3(256), 0, stream>>>(hs, gw, comb, maskbuf);
  k_build_lists<<<dim3(1), dim3(1024), 0, stream>>>(maskbuf, lists, counts, offsets);
  // routed gemm1 (gathered rows, packed by expert)
  k_mlp1<<<dim3(16, 8, 16), dim3(256), 0, stream>>>(hs, w1, Gr, lists, counts, offsets, NMOE);
  // shared gemm1 over all tokens
  k_mlp1<<<dim3(32, 8, 1), dim3(256), 0, stream>>>(hs, sgu, Gs, nullptr, nullptr, nullptr, NSH);
  // shared gemm2: plain store (covers all of d_out)
  k_mlp2<<<dim3(8, 8, 1), dim3(256), 0, stream>>>(Gs, sd, out, nullptr, nullptr, nullptr, nullptr, NSH, 0);
  // routed gemm2: weighted atomic accumulate
  k_mlp2<<<dim3(8, 8, 16), dim3(256), 0, stream>>>(Gr, w2, out, lists, counts, offsets, comb, NMOE, 1);
}

// Round 3
// 239.065 us; speedup vs baseline: 1.6173x; 1.6173x over previous
//
#include <hip/hip_runtime.h>
#include <hip/hip_bf16.h>

// DeepseekV2 MoE layer: M=1024 tokens, H=1024 hidden, E=16 experts (top-6 via
// 8 groups-of-2 -> top-3 groups), N=1024 per-expert intermediate, shared
// expert I=2048. fp32 inputs; GEMMs in bf16 MFMA (threshold 2.2e-2).
// R3: coalesced staging restored (R2 regression), BK=64 + XOR swizzle kept
// (0 bank conflicts), shared expert merged into routed grids, out zeroed +
// all-atomic mlp2 epilogue.

#define M_TOK 1024
#define HDIM  1024
#define NEXP  16
#define NMOE  1024
#define NSH   2048

using bf16x8 = __attribute__((ext_vector_type(8))) short;
using f32x4  = __attribute__((ext_vector_type(4))) float;

static __device__ __forceinline__ short f2b(float x) {
  __hip_bfloat16 b = __float2bfloat16(x);
  return __builtin_bit_cast(short, b);
}

static __device__ __forceinline__ uint4 pack8(float4 a, float4 b) {
  union { short s[8]; uint4 u; } r;
  r.s[0] = f2b(a.x); r.s[1] = f2b(a.y); r.s[2] = f2b(a.z); r.s[3] = f2b(a.w);
  r.s[4] = f2b(b.x); r.s[5] = f2b(b.y); r.s[6] = f2b(b.z); r.s[7] = f2b(b.w);
  return r.u;
}

// LDS tile: rows of 128B (64 bf16), chunk = 16B slot 0..7. XOR swizzle spreads
// the 8 chunks of an 8-row stripe across the 8 4-bank groups (R2: 0 conflicts).
static __device__ __forceinline__ int swz(int row, int chunk) {
  return (row << 7) + (((chunk ^ row) & 7) << 4);
}

// ---------------- router: logits + softmax + grouped top-k ----------------
__global__ __launch_bounds__(256)
void k_router(const float* __restrict__ hs, const float* __restrict__ gw,
              float* __restrict__ comb, unsigned* __restrict__ maskbuf) {
  int wave = threadIdx.x >> 6, lane = threadIdx.x & 63;
  int tok = blockIdx.x * 4 + wave;
  const float* hrow = hs + (size_t)tok * HDIM;
  float acc[16];
#pragma unroll
  for (int e = 0; e < 16; e++) acc[e] = 0.f;
  for (int h0 = 0; h0 < HDIM; h0 += 64) {
    float x = hrow[h0 + lane];
#pragma unroll
    for (int e = 0; e < 16; e++) acc[e] = fmaf(x, gw[e * HDIM + h0 + lane], acc[e]);
  }
#pragma unroll
  for (int e = 0; e < 16; e++) {
    float v = acc[e];
#pragma unroll
    for (int off = 32; off; off >>= 1) v += __shfl_xor(v, off);
    acc[e] = v;
  }
  float mx = acc[0];
#pragma unroll
  for (int e = 1; e < 16; e++) mx = fmaxf(mx, acc[e]);
  float sum = 0.f;
#pragma unroll
  for (int e = 0; e < 16; e++) { acc[e] = __expf(acc[e] - mx); sum += acc[e]; }
  float inv = 1.f / sum;
#pragma unroll
  for (int e = 0; e < 16; e++) acc[e] *= inv;
  float gs[8];
#pragma unroll
  for (int g = 0; g < 8; g++) gs[g] = fmaxf(acc[2 * g], acc[2 * g + 1]);
  unsigned gmask = 0;
  for (int t = 0; t < 3; t++) {
    int best = 0; float bv = -1.f;
#pragma unroll
    for (int g = 0; g < 8; g++) {
      bool take = (((gmask >> g) & 1u) == 0u) && (gs[g] > bv);
      bv = take ? gs[g] : bv;
      best = take ? g : best;
    }
    gmask |= 1u << best;
  }
  unsigned emask = 0;
#pragma unroll
  for (int g = 0; g < 8; g++) if ((gmask >> g) & 1u) emask |= 3u << (2 * g);
  if (lane < 16) comb[tok * 16 + lane] = ((emask >> lane) & 1u) ? acc[lane] : 0.f;
  if (lane == 0) maskbuf[tok] = emask;
}

// ---------------- per-expert token list compaction ----------------
__global__ __launch_bounds__(1024)
void k_build_lists(const unsigned* __restrict__ maskbuf, int* __restrict__ lists,
                   int* __restrict__ counts, int* __restrict__ offsets) {
  int e = threadIdx.x >> 6, lane = threadIdx.x & 63;
  int cnt = 0;
  for (int c = 0; c < 16; c++) {
    int tok = c * 64 + lane;
    bool sel = (maskbuf[tok] >> e) & 1u;
    unsigned long long b = __ballot(sel);
    if (sel) {
      int pos = cnt + __popcll(b & ((1ull << lane) - 1ull));
      lists[e * 1024 + pos] = tok;
    }
    cnt += __popcll(b);
  }
  for (int i = cnt + lane; i < 1024; i += 64) lists[e * 1024 + i] = 0;  // safe tail
  if (lane == 0) counts[e] = cnt;
  __syncthreads();
  if (threadIdx.x == 0) {
    int run = 0;
    for (int ee = 0; ee < 16; ee++) { offsets[ee] = run; run += counts[ee]; }
  }
}

// ---------------- GEMM1: g = silu(A@Wg^T) * (A@Wu^T), bf16 out ----------------
// tile: 128 rows x (64 gate + 64 up) cols, BK=64, 4 waves (2x2), wave 64x(32+32).
// blockIdx.z: 0..15 routed experts, 16..17 shared expert (n-range halves).
__global__ __launch_bounds__(256)
void k_mlp1(const float* __restrict__ A, const float* __restrict__ Wr,
            const float* __restrict__ Ws, __hip_bfloat16* __restrict__ Gr,
            __hip_bfloat16* __restrict__ Gs,
            const int* __restrict__ lists, const int* __restrict__ counts,
            const int* __restrict__ offsets) {
  int z = blockIdx.z;
  bool sh = (z >= NEXP);
  int e = sh ? 0 : z;
  int N = sh ? NSH : NMOE;
  int n0 = blockIdx.x * 64 + (sh ? (z - NEXP) * 1024 : 0);
  int m0 = blockIdx.y * 128;
  int count = sh ? M_TOK : counts[e];
  if (m0 >= count) return;
  int gbase = (sh ? 0 : offsets[e]) + m0;
  const float* We = sh ? Ws : (Wr + (size_t)e * (2 * (size_t)NMOE) * HDIM);
  __hip_bfloat16* G = sh ? Gs : Gr;

  __shared__ short sA[128 * 64];
  __shared__ short sB[128 * 64];  // rows 0-63: gate cols, rows 64-127: up cols
  __shared__ int sTok[128];
  char* cA = (char*)sA; char* cB = (char*)sB;

  int tid = threadIdx.x;
  if (tid < 128) sTok[tid] = sh ? (m0 + tid) : lists[e * 1024 + m0 + tid];
  __syncthreads();

  // staging: thread -> row p*32 + (tid>>3), 16B-bf16 chunk (tid&7) = 32B fp32.
  // 8 lanes/row -> coalesced (2 float4 at +0/+16 within the 32B slot).
  int rg = tid >> 3, ca = tid & 7;
  const float* pA[4]; const float* pB[4];
#pragma unroll
  for (int p = 0; p < 4; p++) {
    int row = p * 32 + rg;
    pA[p] = A + (size_t)sTok[row] * HDIM + ca * 8;
    int brow = (row < 64) ? (n0 + row) : (N + n0 + row - 64);
    pB[p] = We + (size_t)brow * HDIM + ca * 8;
  }

  int lane = tid & 63, wave = tid >> 6;
  int wm = wave >> 1, wn = wave & 1;
  int lrow = lane & 15, lquad = lane >> 4;

  f32x4 acc1[4][2] = {};
  f32x4 acc2[4][2] = {};

  for (int k0 = 0; k0 < HDIM; k0 += 64) {
    float4 a0[4], a1[4], b0[4], b1[4];
#pragma unroll
    for (int p = 0; p < 4; p++) {
      a0[p] = *reinterpret_cast<const float4*>(pA[p] + k0);
      a1[p] = *reinterpret_cast<const float4*>(pA[p] + k0 + 4);
      b0[p] = *reinterpret_cast<const float4*>(pB[p] + k0);
      b1[p] = *reinterpret_cast<const float4*>(pB[p] + k0 + 4);
    }
    __syncthreads();
#pragma unroll
    for (int p = 0; p < 4; p++) {
      int row = p * 32 + rg;
      *reinterpret_cast<uint4*>(cA + swz(row, ca)) = pack8(a0[p], a1[p]);
      *reinterpret_cast<uint4*>(cB + swz(row, ca)) = pack8(b0[p], b1[p]);
    }
    __syncthreads();
#pragma unroll
    for (int ks = 0; ks < 2; ks++) {
      bf16x8 af[4], bg[2], bu[2];
#pragma unroll
      for (int mi = 0; mi < 4; mi++)
        af[mi] = *reinterpret_cast<const bf16x8*>(cA + swz(wm * 64 + mi * 16 + lrow, ks * 4 + lquad));
#pragma unroll
      for (int ni = 0; ni < 2; ni++) {
        bg[ni] = *reinterpret_cast<const bf16x8*>(cB + swz(wn * 32 + ni * 16 + lrow, ks * 4 + lquad));
        bu[ni] = *reinterpret_cast<const bf16x8*>(cB + swz(64 + wn * 32 + ni * 16 + lrow, ks * 4 + lquad));
      }
#pragma unroll
      for (int mi = 0; mi < 4; mi++)
#pragma unroll
        for (int ni = 0; ni < 2; ni++) {
          acc1[mi][ni] = __builtin_amdgcn_mfma_f32_16x16x32_bf16(af[mi], bg[ni], acc1[mi][ni], 0, 0, 0);
          acc2[mi][ni] = __builtin_amdgcn_mfma_f32_16x16x32_bf16(af[mi], bu[ni], acc2[mi][ni], 0, 0, 0);
        }
    }
  }
#pragma unroll
  for (int mi = 0; mi < 4; mi++)
#pragma unroll
    for (int r = 0; r < 4; r++) {
      int li = wm * 64 + mi * 16 + lquad * 4 + r;
      if (m0 + li < count) {
#pragma unroll
        for (int ni = 0; ni < 2; ni++) {
          float x = acc1[mi][ni][r], y = acc2[mi][ni][r];
          float gv = (x / (1.f + __expf(-x))) * y;
          G[(size_t)(gbase + li) * N + (n0 + wn * 32 + ni * 16 + lrow)] = __float2bfloat16(gv);
        }
      }
    }
}

// ---------------- GEMM2: out += g @ W2^T (atomic, weighted for routed) ----------------
// tile: 128 rows x 128 cols, BK=64, 4 waves (2x2), wave 64x64, acc 4x4.
// blockIdx.z: 0..15 routed experts (K=1024), 16 shared (K=2048).
__global__ __launch_bounds__(256)
void k_mlp2(const __hip_bfloat16* __restrict__ Gr, const __hip_bfloat16* __restrict__ Gs,
            const float* __restrict__ Wr, const float* __restrict__ Ws,
            float* __restrict__ out,
            const int* __restrict__ lists, const int* __restrict__ counts,
            const int* __restrict__ offsets, const float* __restrict__ comb) {
  int z = blockIdx.z;
  bool sh = (z >= NEXP);
  int e = sh ? 0 : z;
  int K = sh ? NSH : NMOE;
  int h0 = blockIdx.x * 128;
  int m0 = blockIdx.y * 128;
  int count = sh ? M_TOK : counts[e];
  if (m0 >= count) return;
  int abase = (sh ? 0 : offsets[e]) + m0;
  const __hip_bfloat16* Gm = sh ? Gs : Gr;
  const float* We = sh ? Ws : (Wr + (size_t)e * (size_t)HDIM * NMOE);

  __shared__ short sA[128 * 64];
  __shared__ short sB[128 * 64];
  __shared__ int sTok[128];
  char* cA = (char*)sA; char* cB = (char*)sB;

  int tid = threadIdx.x;
  if (tid < 128) sTok[tid] = sh ? (m0 + tid) : lists[e * 1024 + m0 + tid];
  __syncthreads();

  int rg = tid >> 3, ca = tid & 7;
  const __hip_bfloat16* pA[4]; const float* pB[4];
#pragma unroll
  for (int p = 0; p < 4; p++) {
    int row = p * 32 + rg;
    pA[p] = Gm + (size_t)(abase + row) * K + ca * 8;  // 16B bf16 chunk
    pB[p] = We + (size_t)(h0 + row) * K + ca * 8;     // 32B fp32 slot
  }

  int lane = tid & 63, wave = tid >> 6;
  int wm = wave >> 1, wn = wave & 1;
  int lrow = lane & 15, lquad = lane >> 4;

  f32x4 acc[4][4] = {};

  for (int k0 = 0; k0 < K; k0 += 64) {
    uint4 ua[4]; float4 b0[4], b1[4];
#pragma unroll
    for (int p = 0; p < 4; p++) {
      ua[p] = *reinterpret_cast<const uint4*>(pA[p] + k0);
      b0[p] = *reinterpret_cast<const float4*>(pB[p] + k0);
      b1[p] = *reinterpret_cast<const float4*>(pB[p] + k0 + 4);
    }
    __syncthreads();
#pragma unroll
    for (int p = 0; p < 4; p++) {
      int row = p * 32 + rg;
      *reinterpret_cast<uint4*>(cA + swz(row, ca)) = ua[p];
      *reinterpret_cast<uint4*>(cB + swz(row, ca)) = pack8(b0[p], b1[p]);
    }
    __syncthreads();
#pragma unroll
    for (int ks = 0; ks < 2; ks++) {
      bf16x8 af[4], bfr[4];
#pragma unroll
      for (int i = 0; i < 4; i++) {
        af[i]  = *reinterpret_cast<const bf16x8*>(cA + swz(wm * 64 + i * 16 + lrow, ks * 4 + lquad));
        bfr[i] = *reinterpret_cast<const bf16x8*>(cB + swz(wn * 64 + i * 16 + lrow, ks * 4 + lquad));
      }
#pragma unroll
      for (int mi = 0; mi < 4; mi++)
#pragma unroll
        for (int ni = 0; ni < 4; ni++)
          acc[mi][ni] = __builtin_amdgcn_mfma_f32_16x16x32_bf16(af[mi], bfr[ni], acc[mi][ni], 0, 0, 0);
    }
  }

#pragma unroll
  for (int mi = 0; mi < 4; mi++)
#pragma unroll
    for (int r = 0; r < 4; r++) {
      int li = wm * 64 + mi * 16 + lquad * 4 + r;
      bool ok = (m0 + li) < count;
      int tok = sTok[li];
      float w = sh ? 1.f : comb[tok * 16 + e];
#pragma unroll
      for (int ni = 0; ni < 4; ni++)
        if (ok) atomicAdd(&out[(size_t)tok * HDIM + h0 + wn * 64 + ni * 16 + lrow],
                          acc[mi][ni][r] * w);
    }
}

extern "C" void kernel_launch(void* const* d_in, const int* in_sizes, int n_in,
                              void* d_out, int out_size, void* d_ws, size_t ws_size,
                              hipStream_t stream) {
  const float* hs  = (const float*)d_in[0];
  const float* gw  = (const float*)d_in[1];
  const float* w1  = (const float*)d_in[2];
  const float* w2  = (const float*)d_in[3];
  const float* sgu = (const float*)d_in[4];
  const float* sd  = (const float*)d_in[5];
  float* out = (float*)d_out;
  char* ws = (char*)d_ws;

  float*    comb    = (float*)(ws + 0);          // 65536 B
  unsigned* maskbuf = (unsigned*)(ws + 65536);   // 4096 B
  int*      lists   = (int*)(ws + 69632);        // 65536 B
  int*      counts  = (int*)(ws + 135168);
  int*      offsets = (int*)(ws + 135232);
  __hip_bfloat16* Gr = (__hip_bfloat16*)(ws + 262144);              // 6272*1024*2
  __hip_bfloat16* Gs = (__hip_bfloat16*)(ws + 262144 + 12845056);   // 1024*2048*2
  if (ws_size < (size_t)(262144 + 12845056 + 4194304)) return;

  hipMemsetAsync(out, 0, (size_t)M_TOK * HDIM * sizeof(float), stream);
  k_router<<<dim3(256), dim3(256), 0, stream>>>(hs, gw, comb, maskbuf);
  k_build_lists<<<dim3(1), dim3(1024), 0, stream>>>(maskbuf, lists, counts, offsets);
  // gemm1: routed experts (z=0..15) + shared expert (z=16,17)
  k_mlp1<<<dim3(16, 8, 18), dim3(256), 0, stream>>>(hs, w1, sgu, Gr, Gs,
                                                    lists, counts, offsets);
  // gemm2: routed (z=0..15, weighted) + shared (z=16), all atomicAdd onto zeroed out
  k_mlp2<<<dim3(8, 8, 17), dim3(256), 0, stream>>>(Gr, Gs, w2, sd, out,
                                                   lists, counts, offsets, comb);
}

// Round 6
// 236.365 us; speedup vs baseline: 1.6358x; 1.0114x over previous
//
#include <hip/hip_runtime.h>
#include <hip/hip_bf16.h>

// DeepseekV2 MoE layer: M=1024 tokens, H=1024 hidden, E=16 experts (top-6 via
// 8 groups-of-2 -> top-3 groups), N=1024 per-expert intermediate, shared
// expert I=2048. fp32 inputs; GEMMs in bf16 MFMA (threshold 2.2e-2).
// R4 (2nd resubmit; two container failures): atomic-free mlp2 — routed rows
// stored bf16 to packed Or buffer, shared stores fp32 to out, then k_combine
// gathers 6 rows/token with router weights.

#define M_TOK 1024
#define HDIM  1024
#define NEXP  16
#define NMOE  1024
#define NSH   2048

using bf16x8 = __attribute__((ext_vector_type(8))) short;
using f32x4  = __attribute__((ext_vector_type(4))) float;

static __device__ __forceinline__ short f2b(float x) {
  __hip_bfloat16 b = __float2bfloat16(x);
  return __builtin_bit_cast(short, b);
}
static __device__ __forceinline__ float b2f(short s) {
  return __bfloat162float(__builtin_bit_cast(__hip_bfloat16, s));
}

static __device__ __forceinline__ uint4 pack8(float4 a, float4 b) {
  union { short s[8]; uint4 u; } r;
  r.s[0] = f2b(a.x); r.s[1] = f2b(a.y); r.s[2] = f2b(a.z); r.s[3] = f2b(a.w);
  r.s[4] = f2b(b.x); r.s[5] = f2b(b.y); r.s[6] = f2b(b.z); r.s[7] = f2b(b.w);
  return r.u;
}

// LDS tile: rows of 128B (64 bf16), chunk = 16B slot 0..7. XOR swizzle spreads
// the 8 chunks of an 8-row stripe across the 8 4-bank groups (R2: 0 conflicts).
static __device__ __forceinline__ int swz(int row, int chunk) {
  return (row << 7) + (((chunk ^ row) & 7) << 4);
}

// ---------------- router: logits + softmax + grouped top-k ----------------
__global__ __launch_bounds__(256)
void k_router(const float* __restrict__ hs, const float* __restrict__ gw,
              float* __restrict__ comb, unsigned* __restrict__ maskbuf) {
  int wave = threadIdx.x >> 6, lane = threadIdx.x & 63;
  int tok = blockIdx.x * 4 + wave;
  const float* hrow = hs + (size_t)tok * HDIM;
  float acc[16];
#pragma unroll
  for (int e = 0; e < 16; e++) acc[e] = 0.f;
  for (int h0 = 0; h0 < HDIM; h0 += 64) {
    float x = hrow[h0 + lane];
#pragma unroll
    for (int e = 0; e < 16; e++) acc[e] = fmaf(x, gw[e * HDIM + h0 + lane], acc[e]);
  }
#pragma unroll
  for (int e = 0; e < 16; e++) {
    float v = acc[e];
#pragma unroll
    for (int off = 32; off; off >>= 1) v += __shfl_xor(v, off);
    acc[e] = v;
  }
  float mx = acc[0];
#pragma unroll
  for (int e = 1; e < 16; e++) mx = fmaxf(mx, acc[e]);
  float sum = 0.f;
#pragma unroll
  for (int e = 0; e < 16; e++) { acc[e] = __expf(acc[e] - mx); sum += acc[e]; }
  float inv = 1.f / sum;
#pragma unroll
  for (int e = 0; e < 16; e++) acc[e] *= inv;
  float gs[8];
#pragma unroll
  for (int g = 0; g < 8; g++) gs[g] = fmaxf(acc[2 * g], acc[2 * g + 1]);
  unsigned gmask = 0;
  for (int t = 0; t < 3; t++) {
    int best = 0; float bv = -1.f;
#pragma unroll
    for (int g = 0; g < 8; g++) {
      bool take = (((gmask >> g) & 1u) == 0u) && (gs[g] > bv);
      bv = take ? gs[g] : bv;
      best = take ? g : best;
    }
    gmask |= 1u << best;
  }
  unsigned emask = 0;
#pragma unroll
  for (int g = 0; g < 8; g++) if ((gmask >> g) & 1u) emask |= 3u << (2 * g);
  if (lane < 16) comb[tok * 16 + lane] = ((emask >> lane) & 1u) ? acc[lane] : 0.f;
  if (lane == 0) maskbuf[tok] = emask;
}

// ---------------- per-expert token lists + inverse map ----------------
__global__ __launch_bounds__(1024)
void k_build_lists(const unsigned* __restrict__ maskbuf, const float* __restrict__ comb,
                   int* __restrict__ lists, int* __restrict__ counts,
                   int* __restrict__ offsets, int* __restrict__ tok2row,
                   float* __restrict__ tokw) {
  int e = threadIdx.x >> 6, lane = threadIdx.x & 63;
  int cnt = 0;
  for (int c = 0; c < 16; c++) {
    int tok = c * 64 + lane;
    bool sel = (maskbuf[tok] >> e) & 1u;
    unsigned long long b = __ballot(sel);
    if (sel) {
      int pos = cnt + __popcll(b & ((1ull << lane) - 1ull));
      lists[e * 1024 + pos] = tok;
    }
    cnt += __popcll(b);
  }
  for (int i = cnt + lane; i < 1024; i += 64) lists[e * 1024 + i] = 0;  // safe tail
  if (lane == 0) counts[e] = cnt;
  __syncthreads();
  if (threadIdx.x == 0) {
    int run = 0;
    for (int ee = 0; ee < 16; ee++) { offsets[ee] = run; run += counts[ee]; }
  }
  __syncthreads();
  // inverse map: token -> its 6 packed rows + weights (slot = rank of e in mask)
  int base = offsets[e], n = counts[e];
  for (int i = lane; i < n; i += 64) {
    int tok = lists[e * 1024 + i];
    unsigned em = maskbuf[tok];
    int slot = __popc(em & ((1u << e) - 1u));
    tok2row[tok * 6 + slot] = base + i;
    tokw[tok * 6 + slot] = comb[tok * 16 + e];
  }
}

// ---------------- GEMM1: g = silu(A@Wg^T) * (A@Wu^T), bf16 out ----------------
// tile: 128 rows x (64 gate + 64 up) cols, BK=64, 4 waves (2x2), wave 64x(32+32).
// blockIdx.z: 0..15 routed experts, 16..17 shared expert (n-range halves).
__global__ __launch_bounds__(256)
void k_mlp1(const float* __restrict__ A, const float* __restrict__ Wr,
            const float* __restrict__ Ws, __hip_bfloat16* __restrict__ Gr,
            __hip_bfloat16* __restrict__ Gs,
            const int* __restrict__ lists, const int* __restrict__ counts,
            const int* __restrict__ offsets) {
  int z = blockIdx.z;
  bool sh = (z >= NEXP);
  int e = sh ? 0 : z;
  int N = sh ? NSH : NMOE;
  int n0 = blockIdx.x * 64 + (sh ? (z - NEXP) * 1024 : 0);
  int m0 = blockIdx.y * 128;
  int count = sh ? M_TOK : counts[e];
  if (m0 >= count) return;
  int gbase = (sh ? 0 : offsets[e]) + m0;
  const float* We = sh ? Ws : (Wr + (size_t)e * (2 * (size_t)NMOE) * HDIM);
  __hip_bfloat16* G = sh ? Gs : Gr;

  __shared__ short sA[128 * 64];
  __shared__ short sB[128 * 64];  // rows 0-63: gate cols, rows 64-127: up cols
  __shared__ int sTok[128];
  char* cA = (char*)sA; char* cB = (char*)sB;

  int tid = threadIdx.x;
  if (tid < 128) sTok[tid] = sh ? (m0 + tid) : lists[e * 1024 + m0 + tid];
  __syncthreads();

  // staging: thread -> row p*32 + (tid>>3), 16B-bf16 chunk (tid&7) = 32B fp32.
  int rg = tid >> 3, ca = tid & 7;
  const float* pA[4]; const float* pB[4];
#pragma unroll
  for (int p = 0; p < 4; p++) {
    int row = p * 32 + rg;
    pA[p] = A + (size_t)sTok[row] * HDIM + ca * 8;
    int brow = (row < 64) ? (n0 + row) : (N + n0 + row - 64);
    pB[p] = We + (size_t)brow * HDIM + ca * 8;
  }

  int lane = tid & 63, wave = tid >> 6;
  int wm = wave >> 1, wn = wave & 1;
  int lrow = lane & 15, lquad = lane >> 4;

  f32x4 acc1[4][2] = {};
  f32x4 acc2[4][2] = {};

  for (int k0 = 0; k0 < HDIM; k0 += 64) {
    float4 a0[4], a1[4], b0[4], b1[4];
#pragma unroll
    for (int p = 0; p < 4; p++) {
      a0[p] = *reinterpret_cast<const float4*>(pA[p] + k0);
      a1[p] = *reinterpret_cast<const float4*>(pA[p] + k0 + 4);
      b0[p] = *reinterpret_cast<const float4*>(pB[p] + k0);
      b1[p] = *reinterpret_cast<const float4*>(pB[p] + k0 + 4);
    }
    __syncthreads();
#pragma unroll
    for (int p = 0; p < 4; p++) {
      int row = p * 32 + rg;
      *reinterpret_cast<uint4*>(cA + swz(row, ca)) = pack8(a0[p], a1[p]);
      *reinterpret_cast<uint4*>(cB + swz(row, ca)) = pack8(b0[p], b1[p]);
    }
    __syncthreads();
#pragma unroll
    for (int ks = 0; ks < 2; ks++) {
      bf16x8 af[4], bg[2], bu[2];
#pragma unroll
      for (int mi = 0; mi < 4; mi++)
        af[mi] = *reinterpret_cast<const bf16x8*>(cA + swz(wm * 64 + mi * 16 + lrow, ks * 4 + lquad));
#pragma unroll
      for (int ni = 0; ni < 2; ni++) {
        bg[ni] = *reinterpret_cast<const bf16x8*>(cB + swz(wn * 32 + ni * 16 + lrow, ks * 4 + lquad));
        bu[ni] = *reinterpret_cast<const bf16x8*>(cB + swz(64 + wn * 32 + ni * 16 + lrow, ks * 4 + lquad));
      }
#pragma unroll
      for (int mi = 0; mi < 4; mi++)
#pragma unroll
        for (int ni = 0; ni < 2; ni++) {
          acc1[mi][ni] = __builtin_amdgcn_mfma_f32_16x16x32_bf16(af[mi], bg[ni], acc1[mi][ni], 0, 0, 0);
          acc2[mi][ni] = __builtin_amdgcn_mfma_f32_16x16x32_bf16(af[mi], bu[ni], acc2[mi][ni], 0, 0, 0);
        }
    }
  }
#pragma unroll
  for (int mi = 0; mi < 4; mi++)
#pragma unroll
    for (int r = 0; r < 4; r++) {
      int li = wm * 64 + mi * 16 + lquad * 4 + r;
      if (m0 + li < count) {
#pragma unroll
        for (int ni = 0; ni < 2; ni++) {
          float x = acc1[mi][ni][r], y = acc2[mi][ni][r];
          float gv = (x / (1.f + __expf(-x))) * y;
          G[(size_t)(gbase + li) * N + (n0 + wn * 32 + ni * 16 + lrow)] = __float2bfloat16(gv);
        }
      }
    }
}

// ---------------- GEMM2: routed -> bf16 rows into Or; shared -> fp32 out ----
// tile: 128 rows x 128 cols, BK=64, 4 waves (2x2), wave 64x64, acc 4x4.
// blockIdx.z: 0..15 routed experts (K=1024), 16 shared (K=2048).
__global__ __launch_bounds__(256)
void k_mlp2(const __hip_bfloat16* __restrict__ Gr, const __hip_bfloat16* __restrict__ Gs,
            const float* __restrict__ Wr, const float* __restrict__ Ws,
            __hip_bfloat16* __restrict__ Or, float* __restrict__ out,
            const int* __restrict__ counts, const int* __restrict__ offsets) {
  int z = blockIdx.z;
  bool sh = (z >= NEXP);
  int e = sh ? 0 : z;
  int K = sh ? NSH : NMOE;
  int h0 = blockIdx.x * 128;
  int m0 = blockIdx.y * 128;
  int count = sh ? M_TOK : counts[e];
  if (m0 >= count) return;
  int abase = (sh ? 0 : offsets[e]) + m0;
  const __hip_bfloat16* Gm = sh ? Gs : Gr;
  const float* We = sh ? Ws : (Wr + (size_t)e * (size_t)HDIM * NMOE);

  __shared__ short sA[128 * 64];
  __shared__ short sB[128 * 64];
  char* cA = (char*)sA; char* cB = (char*)sB;

  int tid = threadIdx.x;
  int rg = tid >> 3, ca = tid & 7;
  const __hip_bfloat16* pA[4]; const float* pB[4];
#pragma unroll
  for (int p = 0; p < 4; p++) {
    int row = p * 32 + rg;
    pA[p] = Gm + (size_t)(abase + row) * K + ca * 8;  // 16B bf16 chunk
    pB[p] = We + (size_t)(h0 + row) * K + ca * 8;     // 32B fp32 slot
  }

  int lane = tid & 63, wave = tid >> 6;
  int wm = wave >> 1, wn = wave & 1;
  int lrow = lane & 15, lquad = lane >> 4;

  f32x4 acc[4][4] = {};

  for (int k0 = 0; k0 < K; k0 += 64) {
    uint4 ua[4]; float4 b0[4], b1[4];
#pragma unroll
    for (int p = 0; p < 4; p++) {
      ua[p] = *reinterpret_cast<const uint4*>(pA[p] + k0);
      b0[p] = *reinterpret_cast<const float4*>(pB[p] + k0);
      b1[p] = *reinterpret_cast<const float4*>(pB[p] + k0 + 4);
    }
    __syncthreads();
#pragma unroll
    for (int p = 0; p < 4; p++) {
      int row = p * 32 + rg;
      *reinterpret_cast<uint4*>(cA + swz(row, ca)) = ua[p];
      *reinterpret_cast<uint4*>(cB + swz(row, ca)) = pack8(b0[p], b1[p]);
    }
    __syncthreads();
#pragma unroll
    for (int ks = 0; ks < 2; ks++) {
      bf16x8 af[4], bfr[4];
#pragma unroll
      for (int i = 0; i < 4; i++) {
        af[i]  = *reinterpret_cast<const bf16x8*>(cA + swz(wm * 64 + i * 16 + lrow, ks * 4 + lquad));
        bfr[i] = *reinterpret_cast<const bf16x8*>(cB + swz(wn * 64 + i * 16 + lrow, ks * 4 + lquad));
      }
#pragma unroll
      for (int mi = 0; mi < 4; mi++)
#pragma unroll
        for (int ni = 0; ni < 4; ni++)
          acc[mi][ni] = __builtin_amdgcn_mfma_f32_16x16x32_bf16(af[mi], bfr[ni], acc[mi][ni], 0, 0, 0);
    }
  }

  if (sh) {
#pragma unroll
    for (int mi = 0; mi < 4; mi++)
#pragma unroll
      for (int r = 0; r < 4; r++) {
        int li = wm * 64 + mi * 16 + lquad * 4 + r;
        size_t orow = (size_t)(m0 + li) * HDIM;
#pragma unroll
        for (int ni = 0; ni < 4; ni++)
          out[orow + h0 + wn * 64 + ni * 16 + lrow] = acc[mi][ni][r];
      }
  } else {
#pragma unroll
    for (int mi = 0; mi < 4; mi++)
#pragma unroll
      for (int r = 0; r < 4; r++) {
        int li = wm * 64 + mi * 16 + lquad * 4 + r;
        if (m0 + li < count) {
          size_t orow = (size_t)(abase + li) * HDIM;
#pragma unroll
          for (int ni = 0; ni < 4; ni++)
            Or[orow + h0 + wn * 64 + ni * 16 + lrow] =
                __float2bfloat16(acc[mi][ni][r]);
        }
      }
  }
}

// ---------------- combine: out[tok] += sum_k w_k * Or[row_k] ----------------
__global__ __launch_bounds__(256)
void k_combine(const __hip_bfloat16* __restrict__ Or, const int* __restrict__ tok2row,
               const float* __restrict__ tokw, float* __restrict__ out) {
  int tok = blockIdx.x;
  int c4 = threadIdx.x * 4;
  int rows[6]; float w[6];
#pragma unroll
  for (int k = 0; k < 6; k++) {
    rows[k] = tok2row[tok * 6 + k];
    w[k] = tokw[tok * 6 + k];
  }
  float* op = out + (size_t)tok * HDIM + c4;
  float4 o = *reinterpret_cast<float4*>(op);
#pragma unroll
  for (int k = 0; k < 6; k++) {
    short4 v = *reinterpret_cast<const short4*>(Or + (size_t)rows[k] * HDIM + c4);
    o.x = fmaf(w[k], b2f(v.x), o.x);
    o.y = fmaf(w[k], b2f(v.y), o.y);
    o.z = fmaf(w[k], b2f(v.z), o.z);
    o.w = fmaf(w[k], b2f(v.w), o.w);
  }
  *reinterpret_cast<float4*>(op) = o;
}

extern "C" void kernel_launch(void* const* d_in, const int* in_sizes, int n_in,
                              void* d_out, int out_size, void* d_ws, size_t ws_size,
                              hipStream_t stream) {
  const float* hs  = (const float*)d_in[0];
  const float* gw  = (const float*)d_in[1];
  const float* w1  = (const float*)d_in[2];
  const float* w2  = (const float*)d_in[3];
  const float* sgu = (const float*)d_in[4];
  const float* sd  = (const float*)d_in[5];
  float* out = (float*)d_out;
  char* ws = (char*)d_ws;

  float*    comb    = (float*)(ws + 0);          // 65536 B
  unsigned* maskbuf = (unsigned*)(ws + 65536);   // 4096 B
  int*      lists   = (int*)(ws + 69632);        // 65536 B
  int*      counts  = (int*)(ws + 135168);       // 64 B
  int*      offsets = (int*)(ws + 135232);       // 64 B
  int*      tok2row = (int*)(ws + 139264);       // 1024*6*4 = 24576 B
  float*    tokw    = (float*)(ws + 163840);     // 24576 B
  __hip_bfloat16* Gr = (__hip_bfloat16*)(ws + 262144);    // 6272*1024*2 = 12845056
  __hip_bfloat16* Gs = (__hip_bfloat16*)(ws + 13107200);  // 1024*2048*2 = 4194304
  __hip_bfloat16* Or = (__hip_bfloat16*)(ws + 17301504);  // 6272*1024*2 = 12845056
  if (ws_size < (size_t)(17301504 + 12845056)) return;    // ~30.2 MB scratch

  k_router<<<dim3(256), dim3(256), 0, stream>>>(hs, gw, comb, maskbuf);
  k_build_lists<<<dim3(1), dim3(1024), 0, stream>>>(maskbuf, comb, lists, counts,
                                                    offsets, tok2row, tokw);
  // gemm1: routed experts (z=0..15) + shared expert (z=16,17)
  k_mlp1<<<dim3(16, 8, 18), dim3(256), 0, stream>>>(hs, w1, sgu, Gr, Gs,
                                                    lists, counts, offsets);
  // gemm2: routed -> Or rows (bf16), shared (z=16) -> out (covers all elements)
  k_mlp2<<<dim3(8, 8, 17), dim3(256), 0, stream>>>(Gr, Gs, w2, sd, Or, out,
                                                   counts, offsets);
  // gather + weighted sum per token
  k_combine<<<dim3(1024), dim3(256), 0, stream>>>(Or, tok2row, tokw, out);
}

// Round 7
// 173.588 us; speedup vs baseline: 2.2273x; 1.3616x over previous
//
#include <hip/hip_runtime.h>
#include <hip/hip_bf16.h>

// DeepseekV2 MoE layer: M=1024 tokens, H=1024 hidden, E=16 experts (top-6 via
// 8 groups-of-2 -> top-3 groups), N=1024 per-expert intermediate, shared
// expert I=2048. fp32 inputs; GEMMs in bf16 MFMA (threshold 2.2e-2).
// R7: mlp2 rebuilt — 64x128 tile (2x blocks), LDS-transposed epilogue giving
// coalesced 16B/lane stores (kills the 4.5x write amplification seen in R6:
// WRITE_SIZE 76MB vs 17MB ideal from scalar 2B partial-line stores).

#define M_TOK 1024
#define HDIM  1024
#define NEXP  16
#define NMOE  1024
#define NSH   2048

using bf16x8 = __attribute__((ext_vector_type(8))) short;
using f32x4  = __attribute__((ext_vector_type(4))) float;

static __device__ __forceinline__ short f2b(float x) {
  __hip_bfloat16 b = __float2bfloat16(x);
  return __builtin_bit_cast(short, b);
}
static __device__ __forceinline__ float b2f(short s) {
  return __bfloat162float(__builtin_bit_cast(__hip_bfloat16, s));
}

static __device__ __forceinline__ uint4 pack8(float4 a, float4 b) {
  union { short s[8]; uint4 u; } r;
  r.s[0] = f2b(a.x); r.s[1] = f2b(a.y); r.s[2] = f2b(a.z); r.s[3] = f2b(a.w);
  r.s[4] = f2b(b.x); r.s[5] = f2b(b.y); r.s[6] = f2b(b.z); r.s[7] = f2b(b.w);
  return r.u;
}

// LDS staging tile: rows of 128B (64 bf16), chunk = 16B slot 0..7. XOR swizzle
// spreads the 8 chunks of an 8-row stripe across the 8 4-bank groups.
static __device__ __forceinline__ int swz(int row, int chunk) {
  return (row << 7) + (((chunk ^ row) & 7) << 4);
}

// ---------------- router: logits + softmax + grouped top-k ----------------
__global__ __launch_bounds__(256)
void k_router(const float* __restrict__ hs, const float* __restrict__ gw,
              float* __restrict__ comb, unsigned* __restrict__ maskbuf) {
  int wave = threadIdx.x >> 6, lane = threadIdx.x & 63;
  int tok = blockIdx.x * 4 + wave;
  const float* hrow = hs + (size_t)tok * HDIM;
  float acc[16];
#pragma unroll
  for (int e = 0; e < 16; e++) acc[e] = 0.f;
  for (int h0 = 0; h0 < HDIM; h0 += 64) {
    float x = hrow[h0 + lane];
#pragma unroll
    for (int e = 0; e < 16; e++) acc[e] = fmaf(x, gw[e * HDIM + h0 + lane], acc[e]);
  }
#pragma unroll
  for (int e = 0; e < 16; e++) {
    float v = acc[e];
#pragma unroll
    for (int off = 32; off; off >>= 1) v += __shfl_xor(v, off);
    acc[e] = v;
  }
  float mx = acc[0];
#pragma unroll
  for (int e = 1; e < 16; e++) mx = fmaxf(mx, acc[e]);
  float sum = 0.f;
#pragma unroll
  for (int e = 0; e < 16; e++) { acc[e] = __expf(acc[e] - mx); sum += acc[e]; }
  float inv = 1.f / sum;
#pragma unroll
  for (int e = 0; e < 16; e++) acc[e] *= inv;
  float gs[8];
#pragma unroll
  for (int g = 0; g < 8; g++) gs[g] = fmaxf(acc[2 * g], acc[2 * g + 1]);
  unsigned gmask = 0;
  for (int t = 0; t < 3; t++) {
    int best = 0; float bv = -1.f;
#pragma unroll
    for (int g = 0; g < 8; g++) {
      bool take = (((gmask >> g) & 1u) == 0u) && (gs[g] > bv);
      bv = take ? gs[g] : bv;
      best = take ? g : best;
    }
    gmask |= 1u << best;
  }
  unsigned emask = 0;
#pragma unroll
  for (int g = 0; g < 8; g++) if ((gmask >> g) & 1u) emask |= 3u << (2 * g);
  if (lane < 16) comb[tok * 16 + lane] = ((emask >> lane) & 1u) ? acc[lane] : 0.f;
  if (lane == 0) maskbuf[tok] = emask;
}

// ---------------- per-expert token lists + inverse map ----------------
__global__ __launch_bounds__(1024)
void k_build_lists(const unsigned* __restrict__ maskbuf, const float* __restrict__ comb,
                   int* __restrict__ lists, int* __restrict__ counts,
                   int* __restrict__ offsets, int* __restrict__ tok2row,
                   float* __restrict__ tokw) {
  int e = threadIdx.x >> 6, lane = threadIdx.x & 63;
  int cnt = 0;
  for (int c = 0; c < 16; c++) {
    int tok = c * 64 + lane;
    bool sel = (maskbuf[tok] >> e) & 1u;
    unsigned long long b = __ballot(sel);
    if (sel) {
      int pos = cnt + __popcll(b & ((1ull << lane) - 1ull));
      lists[e * 1024 + pos] = tok;
    }
    cnt += __popcll(b);
  }
  for (int i = cnt + lane; i < 1024; i += 64) lists[e * 1024 + i] = 0;  // safe tail
  if (lane == 0) counts[e] = cnt;
  __syncthreads();
  if (threadIdx.x == 0) {
    int run = 0;
    for (int ee = 0; ee < 16; ee++) { offsets[ee] = run; run += counts[ee]; }
  }
  __syncthreads();
  // inverse map: token -> its 6 packed rows + weights (slot = rank of e in mask)
  int base = offsets[e], n = counts[e];
  for (int i = lane; i < n; i += 64) {
    int tok = lists[e * 1024 + i];
    unsigned em = maskbuf[tok];
    int slot = __popc(em & ((1u << e) - 1u));
    tok2row[tok * 6 + slot] = base + i;
    tokw[tok * 6 + slot] = comb[tok * 16 + e];
  }
}

// ---------------- GEMM1: g = silu(A@Wg^T) * (A@Wu^T), bf16 out ----------------
// tile: 128 rows x (64 gate + 64 up) cols, BK=64, 4 waves (2x2), wave 64x(32+32).
// blockIdx.z: 0..15 routed experts, 16..17 shared expert (n-range halves).
__global__ __launch_bounds__(256)
void k_mlp1(const float* __restrict__ A, const float* __restrict__ Wr,
            const float* __restrict__ Ws, __hip_bfloat16* __restrict__ Gr,
            __hip_bfloat16* __restrict__ Gs,
            const int* __restrict__ lists, const int* __restrict__ counts,
            const int* __restrict__ offsets) {
  int z = blockIdx.z;
  bool sh = (z >= NEXP);
  int e = sh ? 0 : z;
  int N = sh ? NSH : NMOE;
  int n0 = blockIdx.x * 64 + (sh ? (z - NEXP) * 1024 : 0);
  int m0 = blockIdx.y * 128;
  int count = sh ? M_TOK : counts[e];
  if (m0 >= count) return;
  int gbase = (sh ? 0 : offsets[e]) + m0;
  const float* We = sh ? Ws : (Wr + (size_t)e * (2 * (size_t)NMOE) * HDIM);
  __hip_bfloat16* G = sh ? Gs : Gr;

  __shared__ short sA[128 * 64];
  __shared__ short sB[128 * 64];  // rows 0-63: gate cols, rows 64-127: up cols
  __shared__ int sTok[128];
  char* cA = (char*)sA; char* cB = (char*)sB;

  int tid = threadIdx.x;
  if (tid < 128) sTok[tid] = sh ? (m0 + tid) : lists[e * 1024 + m0 + tid];
  __syncthreads();

  // staging: thread -> row p*32 + (tid>>3), 16B-bf16 chunk (tid&7) = 32B fp32.
  int rg = tid >> 3, ca = tid & 7;
  const float* pA[4]; const float* pB[4];
#pragma unroll
  for (int p = 0; p < 4; p++) {
    int row = p * 32 + rg;
    pA[p] = A + (size_t)sTok[row] * HDIM + ca * 8;
    int brow = (row < 64) ? (n0 + row) : (N + n0 + row - 64);
    pB[p] = We + (size_t)brow * HDIM + ca * 8;
  }

  int lane = tid & 63, wave = tid >> 6;
  int wm = wave >> 1, wn = wave & 1;
  int lrow = lane & 15, lquad = lane >> 4;

  f32x4 acc1[4][2] = {};
  f32x4 acc2[4][2] = {};

  for (int k0 = 0; k0 < HDIM; k0 += 64) {
    float4 a0[4], a1[4], b0[4], b1[4];
#pragma unroll
    for (int p = 0; p < 4; p++) {
      a0[p] = *reinterpret_cast<const float4*>(pA[p] + k0);
      a1[p] = *reinterpret_cast<const float4*>(pA[p] + k0 + 4);
      b0[p] = *reinterpret_cast<const float4*>(pB[p] + k0);
      b1[p] = *reinterpret_cast<const float4*>(pB[p] + k0 + 4);
    }
    __syncthreads();
#pragma unroll
    for (int p = 0; p < 4; p++) {
      int row = p * 32 + rg;
      *reinterpret_cast<uint4*>(cA + swz(row, ca)) = pack8(a0[p], a1[p]);
      *reinterpret_cast<uint4*>(cB + swz(row, ca)) = pack8(b0[p], b1[p]);
    }
    __syncthreads();
#pragma unroll
    for (int ks = 0; ks < 2; ks++) {
      bf16x8 af[4], bg[2], bu[2];
#pragma unroll
      for (int mi = 0; mi < 4; mi++)
        af[mi] = *reinterpret_cast<const bf16x8*>(cA + swz(wm * 64 + mi * 16 + lrow, ks * 4 + lquad));
#pragma unroll
      for (int ni = 0; ni < 2; ni++) {
        bg[ni] = *reinterpret_cast<const bf16x8*>(cB + swz(wn * 32 + ni * 16 + lrow, ks * 4 + lquad));
        bu[ni] = *reinterpret_cast<const bf16x8*>(cB + swz(64 + wn * 32 + ni * 16 + lrow, ks * 4 + lquad));
      }
#pragma unroll
      for (int mi = 0; mi < 4; mi++)
#pragma unroll
        for (int ni = 0; ni < 2; ni++) {
          acc1[mi][ni] = __builtin_amdgcn_mfma_f32_16x16x32_bf16(af[mi], bg[ni], acc1[mi][ni], 0, 0, 0);
          acc2[mi][ni] = __builtin_amdgcn_mfma_f32_16x16x32_bf16(af[mi], bu[ni], acc2[mi][ni], 0, 0, 0);
        }
    }
  }
#pragma unroll
  for (int mi = 0; mi < 4; mi++)
#pragma unroll
    for (int r = 0; r < 4; r++) {
      int li = wm * 64 + mi * 16 + lquad * 4 + r;
      if (m0 + li < count) {
#pragma unroll
        for (int ni = 0; ni < 2; ni++) {
          float x = acc1[mi][ni][r], y = acc2[mi][ni][r];
          float gv = (x / (1.f + __expf(-x))) * y;
          G[(size_t)(gbase + li) * N + (n0 + wn * 32 + ni * 16 + lrow)] = __float2bfloat16(gv);
        }
      }
    }
}

// ---------------- GEMM2: routed -> bf16 rows into Or; shared -> fp32 out ----
// tile: 64 rows x 128 cols, BK=64, 4 waves (2x2), wave 32x64, acc 2x4.
// Epilogue bounces through LDS so global stores are 16B/lane coalesced.
// blockIdx.z: 0..15 routed experts (K=1024), 16 shared (K=2048).
#define EPS 136  // epilogue LDS row stride in elements (pad vs 128)
__global__ __launch_bounds__(256)
void k_mlp2(const __hip_bfloat16* __restrict__ Gr, const __hip_bfloat16* __restrict__ Gs,
            const float* __restrict__ Wr, const float* __restrict__ Ws,
            __hip_bfloat16* __restrict__ Or, float* __restrict__ out,
            const int* __restrict__ counts, const int* __restrict__ offsets) {
  int z = blockIdx.z;
  bool sh = (z >= NEXP);
  int e = sh ? 0 : z;
  int K = sh ? NSH : NMOE;
  int h0 = blockIdx.x * 128;
  int m0 = blockIdx.y * 64;
  int count = sh ? M_TOK : counts[e];
  if (m0 >= count) return;
  int abase = (sh ? 0 : offsets[e]) + m0;
  const __hip_bfloat16* Gm = sh ? Gs : Gr;
  const float* We = sh ? Ws : (Wr + (size_t)e * (size_t)HDIM * NMOE);

  __shared__ short smem[12288];  // 24KB: sA[64*64] + sB[128*64]; epilogue reuses
  char* cA = (char*)smem;
  char* cB = (char*)(smem + 4096);

  int tid = threadIdx.x;
  // A: row tid>>2 (0..63), chunks {tid&3, (tid&3)+4} (16B bf16 each)
  int rA = tid >> 2, ca2 = tid & 3;
  const __hip_bfloat16* pA = Gm + (size_t)(abase + rA) * K + ca2 * 8;
  // B: 4 passes of rows p*32 + (tid>>3), chunk tid&7 (32B fp32 -> 16B bf16)
  int rgB = tid >> 3, cb = tid & 7;
  const float* pB[4];
#pragma unroll
  for (int p = 0; p < 4; p++)
    pB[p] = We + (size_t)(h0 + p * 32 + rgB) * K + cb * 8;

  int lane = tid & 63, wave = tid >> 6;
  int wm = wave >> 1, wn = wave & 1;
  int lrow = lane & 15, lquad = lane >> 4;

  f32x4 acc[2][4] = {};

  for (int k0 = 0; k0 < K; k0 += 64) {
    uint4 ua0 = *reinterpret_cast<const uint4*>(pA + k0);
    uint4 ua1 = *reinterpret_cast<const uint4*>(pA + k0 + 32);
    float4 b0[4], b1[4];
#pragma unroll
    for (int p = 0; p < 4; p++) {
      b0[p] = *reinterpret_cast<const float4*>(pB[p] + k0);
      b1[p] = *reinterpret_cast<const float4*>(pB[p] + k0 + 4);
    }
    __syncthreads();
    *reinterpret_cast<uint4*>(cA + swz(rA, ca2)) = ua0;
    *reinterpret_cast<uint4*>(cA + swz(rA, ca2 + 4)) = ua1;
#pragma unroll
    for (int p = 0; p < 4; p++)
      *reinterpret_cast<uint4*>(cB + swz(p * 32 + rgB, cb)) = pack8(b0[p], b1[p]);
    __syncthreads();
#pragma unroll
    for (int ks = 0; ks < 2; ks++) {
      bf16x8 af[2], bfr[4];
#pragma unroll
      for (int i = 0; i < 2; i++)
        af[i] = *reinterpret_cast<const bf16x8*>(cA + swz(wm * 32 + i * 16 + lrow, ks * 4 + lquad));
#pragma unroll
      for (int i = 0; i < 4; i++)
        bfr[i] = *reinterpret_cast<const bf16x8*>(cB + swz(wn * 64 + i * 16 + lrow, ks * 4 + lquad));
#pragma unroll
      for (int mi = 0; mi < 2; mi++)
#pragma unroll
        for (int ni = 0; ni < 4; ni++)
          acc[mi][ni] = __builtin_amdgcn_mfma_f32_16x16x32_bf16(af[mi], bfr[ni], acc[mi][ni], 0, 0, 0);
    }
  }
  __syncthreads();  // staging done everywhere; safe to reuse smem

  if (!sh) {
    // bf16 epilogue: acc -> LDS [64][EPS] -> coalesced 16B stores to Or
    short* epi = smem;
#pragma unroll
    for (int mi = 0; mi < 2; mi++)
#pragma unroll
      for (int ni = 0; ni < 4; ni++)
#pragma unroll
        for (int r = 0; r < 4; r++) {
          int row = wm * 32 + mi * 16 + lquad * 4 + r;
          int col = wn * 64 + ni * 16 + lrow;
          epi[row * EPS + col] = f2b(acc[mi][ni][r]);
        }
    __syncthreads();
    int row = tid >> 2, c16 = tid & 3;
    bool ok = (m0 + row) < count;
    size_t obase = (size_t)(abase + row) * HDIM + h0;
    if (ok) {
#pragma unroll
      for (int j = 0; j < 4; j++) {
        int chunk = c16 + 4 * j;  // lanes 0-3 -> 64B contiguous per row
        *reinterpret_cast<uint4*>(Or + obase + chunk * 8) =
            *reinterpret_cast<const uint4*>(epi + row * EPS + chunk * 8);
      }
    }
  } else {
    // fp32 epilogue in two 32-row passes: acc -> LDS [32][EPS] -> 16B stores
    float* epi32 = reinterpret_cast<float*>(smem);
#pragma unroll
    for (int p = 0; p < 2; p++) {
      if (wm == p) {
#pragma unroll
        for (int mi = 0; mi < 2; mi++)
#pragma unroll
          for (int ni = 0; ni < 4; ni++)
#pragma unroll
            for (int r = 0; r < 4; r++) {
              int row = mi * 16 + lquad * 4 + r;
              int col = wn * 64 + ni * 16 + lrow;
              epi32[row * EPS + col] = acc[mi][ni][r];
            }
      }
      __syncthreads();
      int row = tid >> 3, c = tid & 7;
      size_t obase = (size_t)(m0 + p * 32 + row) * HDIM + h0;
#pragma unroll
      for (int j = 0; j < 4; j++) {
        int chunk = c + 8 * j;  // lanes 0-7 -> 128B contiguous per row
        *reinterpret_cast<float4*>(out + obase + chunk * 4) =
            *reinterpret_cast<const float4*>(epi32 + row * EPS + chunk * 4);
      }
      __syncthreads();
    }
  }
}

// ---------------- combine: out[tok] += sum_k w_k * Or[row_k] ----------------
__global__ __launch_bounds__(256)
void k_combine(const __hip_bfloat16* __restrict__ Or, const int* __restrict__ tok2row,
               const float* __restrict__ tokw, float* __restrict__ out) {
  int tok = blockIdx.x;
  int c4 = threadIdx.x * 4;
  int rows[6]; float w[6];
#pragma unroll
  for (int k = 0; k < 6; k++) {
    rows[k] = tok2row[tok * 6 + k];
    w[k] = tokw[tok * 6 + k];
  }
  float* op = out + (size_t)tok * HDIM + c4;
  float4 o = *reinterpret_cast<float4*>(op);
#pragma unroll
  for (int k = 0; k < 6; k++) {
    short4 v = *reinterpret_cast<const short4*>(Or + (size_t)rows[k] * HDIM + c4);
    o.x = fmaf(w[k], b2f(v.x), o.x);
    o.y = fmaf(w[k], b2f(v.y), o.y);
    o.z = fmaf(w[k], b2f(v.z), o.z);
    o.w = fmaf(w[k], b2f(v.w), o.w);
  }
  *reinterpret_cast<float4*>(op) = o;
}

extern "C" void kernel_launch(void* const* d_in, const int* in_sizes, int n_in,
                              void* d_out, int out_size, void* d_ws, size_t ws_size,
                              hipStream_t stream) {
  const float* hs  = (const float*)d_in[0];
  const float* gw  = (const float*)d_in[1];
  const float* w1  = (const float*)d_in[2];
  const float* w2  = (const float*)d_in[3];
  const float* sgu = (const float*)d_in[4];
  const float* sd  = (const float*)d_in[5];
  float* out = (float*)d_out;
  char* ws = (char*)d_ws;

  float*    comb    = (float*)(ws + 0);          // 65536 B
  unsigned* maskbuf = (unsigned*)(ws + 65536);   // 4096 B
  int*      lists   = (int*)(ws + 69632);        // 65536 B
  int*      counts  = (int*)(ws + 135168);       // 64 B
  int*      offsets = (int*)(ws + 135232);       // 64 B
  int*      tok2row = (int*)(ws + 139264);       // 24576 B
  float*    tokw    = (float*)(ws + 163840);     // 24576 B
  __hip_bfloat16* Gr = (__hip_bfloat16*)(ws + 262144);    // 6272*1024*2 = 12845056
  __hip_bfloat16* Gs = (__hip_bfloat16*)(ws + 13107200);  // 1024*2048*2 = 4194304
  __hip_bfloat16* Or = (__hip_bfloat16*)(ws + 17301504);  // 6272*1024*2 = 12845056
  if (ws_size < (size_t)(17301504 + 12845056)) return;    // ~30.2 MB scratch

  k_router<<<dim3(256), dim3(256), 0, stream>>>(hs, gw, comb, maskbuf);
  k_build_lists<<<dim3(1), dim3(1024), 0, stream>>>(maskbuf, comb, lists, counts,
                                                    offsets, tok2row, tokw);
  // gemm1: routed experts (z=0..15) + shared expert (z=16,17)
  k_mlp1<<<dim3(16, 8, 18), dim3(256), 0, stream>>>(hs, w1, sgu, Gr, Gs,
                                                    lists, counts, offsets);
  // gemm2: routed -> Or rows (bf16), shared (z=16) -> out (covers all elements)
  k_mlp2<<<dim3(8, 16, 17), dim3(256), 0, stream>>>(Gr, Gs, w2, sd, Or, out,
                                                    counts, offsets);
  // gather + weighted sum per token
  k_combine<<<dim3(1024), dim3(256), 0, stream>>>(Or, tok2row, tokw, out);
}